// Round 16
// baseline (1842.397 us; speedup 1.0000x reference)
//
#include <hip/hip_runtime.h>
#include <math.h>

#define B_ 4
#define L_ 321
#define D_ 192
#define DI_ 384
#define E_ 768      // 2*DI
#define R_ 12
#define N_ 16
#define DEPTH_ 24
#define XD 44       // R + 2N

#define NC_ 21      // number of scan chunks
#define LC_ 16      // chunk length (NC_*LC_ >= L_)

typedef __attribute__((ext_vector_type(8))) short bf16x8;
typedef __attribute__((ext_vector_type(4))) float f32x4;
typedef unsigned short ushort_t;

__device__ __forceinline__ float silu_f(float x) { return x / (1.f + __expf(-x)); }

__device__ __forceinline__ ushort_t f2bf(float x) {
    union { float f; unsigned u; } v; v.f = x;
    return (ushort_t)((v.u + 0x7fffu + ((v.u >> 16) & 1u)) >> 16);
}
__device__ __forceinline__ float bf2f(ushort_t h) {
    union { unsigned u; float f; } v; v.u = ((unsigned)h) << 16; return v.f;
}

// ---------------- one-shot multi-segment f32 -> bf16 (weights) ----------------
__global__ void cvt_bf16_multi(const float* __restrict__ s0, ushort_t* __restrict__ d0, int n0,
                               const float* __restrict__ s1, ushort_t* __restrict__ d1, int n1,
                               const float* __restrict__ s2, ushort_t* __restrict__ d2, int n2,
                               const float* __restrict__ s3, ushort_t* __restrict__ d3, int n3,
                               const float* __restrict__ s4, ushort_t* __restrict__ d4, int n4) {
    int total = n0 + n1 + n2 + n3 + n4;
    for (int i = blockIdx.x * blockDim.x + threadIdx.x; i < total; i += gridDim.x * blockDim.x) {
        int j = i;
        const float* s; ushort_t* d;
        if (j < n0) { s = s0; d = d0; }
        else { j -= n0;
            if (j < n1) { s = s1; d = d1; }
            else { j -= n1;
                if (j < n2) { s = s2; d = d2; }
                else { j -= n2;
                    if (j < n3) { s = s3; d = d3; }
                    else { j -= n3; s = s4; d = d4; }
                }
            }
        }
        d[j] = f2bf(s[j]);
    }
}

// ---------------- im2col for patch embed (writes bf16) ----------------
__global__ void im2col_kernel(const float* __restrict__ xs, const float* __restrict__ xt,
                              ushort_t* __restrict__ pm) {
    int p_all = blockIdx.x % 320;
    int b = blockIdx.x / 320;
    const float* src; int i, j, W;
    if (p_all < 64) { int p = p_all; i = p >> 3; j = p & 7; W = 128; src = xt + (size_t)b*3*128*128; }
    else            { int p = p_all - 64; i = p >> 4; j = p & 15; W = 256; src = xs + (size_t)b*3*256*256; }
    ushort_t* dst = pm + (size_t)blockIdx.x * 768;
    for (int m = threadIdx.x; m < 768; m += blockDim.x) {
        int c = m >> 8, rem = m & 255, pp = rem >> 4, qq = rem & 15;
        dst[m] = f2bf(src[(size_t)(c*W + i*16 + pp)*W + j*16 + qq]);
    }
}

// ---------------- scatter tokens + cls + pos -> residual, fused rmsnorm -> hn ----------------
__global__ void tok_rms(const float* __restrict__ tokmat, const float* __restrict__ pb,
                        const float* __restrict__ cls, const float* __restrict__ pos,
                        const float* __restrict__ normw,
                        float* __restrict__ residual, ushort_t* __restrict__ hn) {
    int blk = blockIdx.x;
    int b = blk / L_, t = blk % L_;
    int d = threadIdx.x;
    float v;
    if (t == 160) v = cls[d];
    else {
        int p = (t < 160) ? t : t - 1;
        v = tokmat[(size_t)(b*320 + p)*D_ + d] + pb[d];
    }
    v += pos[t*D_ + d];
    residual[(size_t)blk*D_ + d] = v;
    float sq = v * v;
#pragma unroll
    for (int m = 1; m < 64; m <<= 1) sq += __shfl_xor(sq, m, 64);
    __shared__ float part[3];
    int wave = d >> 6, lane = d & 63;
    if (lane == 0) part[wave] = sq;
    __syncthreads();
    float tot = part[0] + part[1] + part[2];
    float scale = rsqrtf(tot / (float)D_ + 1e-5f);
    hn[(size_t)blk*D_ + d] = f2bf(v * scale * normw[d]);
}

// ---------------- MFMA bf16 GEMM: C(MxN) = A(MxK,bf16) * B(NxK,bf16)^T ----------------
// KK compile-time. CMODE 0: C f32.  CMODE 1: C bf16.
template<int WM, int WN, int MFR, int NFR, int CMODE, int KK>
__global__ __launch_bounds__(WM*WN*64) void mfma_gemm(const ushort_t* __restrict__ A,
                          const ushort_t* __restrict__ Bw,
                          float* __restrict__ Cf, ushort_t* __restrict__ Ch,
                          int M, int N) {
    constexpr int BM = WM * MFR * 16;
    constexpr int BN = WN * NFR * 16;
    int bx = blockIdx.x, by = blockIdx.y;
    int wave = threadIdx.x >> 6, lane = threadIdx.x & 63;
    int wr = wave / WN, wc = wave % WN;
    int m0 = by * BM + wr * MFR * 16;
    int n0 = bx * BN + wc * NFR * 16;
    int lrow = lane & 15;
    int lk   = (lane >> 4) * 8;

    f32x4 acc[MFR][NFR];
#pragma unroll
    for (int i = 0; i < MFR; ++i)
#pragma unroll
        for (int j = 0; j < NFR; ++j) acc[i][j] = (f32x4){0.f, 0.f, 0.f, 0.f};

#pragma unroll 6
    for (int k0 = 0; k0 < KK; k0 += 32) {
        bf16x8 a[MFR], b[NFR];
#pragma unroll
        for (int i = 0; i < MFR; ++i) {
            int r = m0 + i*16 + lrow; r = min(r, M - 1);
            a[i] = *(const bf16x8*)(A + (size_t)r*KK + k0 + lk);
        }
#pragma unroll
        for (int jn = 0; jn < NFR; ++jn) {
            int c = n0 + jn*16 + lrow; c = min(c, N - 1);
            b[jn] = *(const bf16x8*)(Bw + (size_t)c*KK + k0 + lk);
        }
#pragma unroll
        for (int i = 0; i < MFR; ++i)
#pragma unroll
            for (int jn = 0; jn < NFR; ++jn)
                acc[i][jn] = __builtin_amdgcn_mfma_f32_16x16x32_bf16(a[i], b[jn], acc[i][jn], 0, 0, 0);
    }

    int crow = (lane >> 4) * 4;
    int ccol = lane & 15;
#pragma unroll
    for (int i = 0; i < MFR; ++i)
#pragma unroll
        for (int jn = 0; jn < NFR; ++jn) {
            int c = n0 + jn*16 + ccol;
            if (c >= N) continue;
#pragma unroll
            for (int j = 0; j < 4; ++j) {
                int r = m0 + i*16 + crow + j;
                if (r < M) {
                    if (CMODE == 0) Cf[(size_t)r*N + c] = acc[i][jn][j];
                    else            Ch[(size_t)r*N + c] = f2bf(acc[i][jn][j]);
                }
            }
        }
}

// ---------------- fused conv + xdbl GEMM + scan phase 1 ----------------
// grid (NC_, B_, 2), 384 threads (6 waves).
__global__ __launch_bounds__(384) void scan1_conv(
    const ushort_t* __restrict__ xzb,
    const ushort_t* __restrict__ Wxf, const ushort_t* __restrict__ Wxbw,
    const float* __restrict__ cw, const float* __restrict__ cb,
    const float* __restrict__ cwb, const float* __restrict__ cbb,
    const float* __restrict__ Wdt, const float* __restrict__ bdt,
    const float* __restrict__ Wdtb, const float* __restrict__ bdtb,
    const float* __restrict__ Alog, const float* __restrict__ Alogb,
    ushort_t* __restrict__ xc_f, ushort_t* __restrict__ xc_b,
    float* __restrict__ xdbl_f, float* __restrict__ xdbl_b,
    float* __restrict__ hloc, float* __restrict__ aprod) {
    int c = blockIdx.x, b = blockIdx.y, br = blockIdx.z;
    int tid = threadIdx.x, wave = tid >> 6, lane = tid & 63;
    const ushort_t* Wx = br ? Wxbw : Wxf;
    const float* cwp = br ? cwb : cw;
    const float* cbp = br ? cbb : cb;
    const float* Wd = br ? Wdtb : Wdt;
    const float* bd = br ? bdtb : bdt;
    const float* Al = br ? Alogb : Alog;
    ushort_t* xcout = br ? xc_b : xc_f;
    float* xdout = br ? xdbl_b : xdbl_f;

    __shared__ ushort_t sxc[LC_][DI_ + 8];
    __shared__ float sxd[LC_][48];
    int lbeg = c * LC_;
    int len = min(lbeg + LC_, L_) - lbeg;
    int d = tid;

    float4 w4 = *(const float4*)(cwp + (size_t)d*4);
    float b0 = cbp[d];
    const ushort_t* xrow = xzb + (size_t)b*L_*E_ + d;
    float u[LC_];
    if (len == LC_) {
        float xr[LC_ + 3];
#pragma unroll
        for (int t2 = 0; t2 < LC_ + 3; ++t2) {
            int t = lbeg - 3 + t2;
            float v = 0.f;
            if (t >= 0) { int tr = br ? (L_ - 1 - t) : t; v = bf2f(xrow[(size_t)tr*E_]); }
            xr[t2] = v;
        }
#pragma unroll
        for (int l2 = 0; l2 < LC_; ++l2) {
            float acc = b0;
            acc = fmaf(w4.x, xr[l2 + 0], acc);
            acc = fmaf(w4.y, xr[l2 + 1], acc);
            acc = fmaf(w4.z, xr[l2 + 2], acc);
            acc = fmaf(w4.w, xr[l2 + 3], acc);
            ushort_t hv = f2bf(silu_f(acc));
            sxc[l2][d] = hv;
            u[l2] = bf2f(hv);
            xcout[((size_t)b*L_ + lbeg + l2)*DI_ + d] = hv;
        }
    } else {
        for (int l2 = 0; l2 < len; ++l2) {
            int l = lbeg + l2;
            float acc = b0;
#pragma unroll
            for (int k = 0; k < 4; ++k) {
                int t = l - 3 + k;
                if (t >= 0) {
                    int tr = br ? (L_ - 1 - t) : t;
                    acc = fmaf(((const float*)&w4)[k], bf2f(xrow[(size_t)tr*E_]), acc);
                }
            }
            ushort_t hv = f2bf(silu_f(acc));
            sxc[l2][d] = hv;
            u[l2] = bf2f(hv);
            xcout[((size_t)b*L_ + lbeg + l2)*DI_ + d] = hv;
        }
    }
    __syncthreads();

    if (wave < 3) {
        int lrow = lane & 15, lk = (lane >> 4) * 8;
        int ar = min(lrow, len - 1);
        int bcol = min(wave * 16 + lrow, XD - 1);
        f32x4 acc = (f32x4){0.f, 0.f, 0.f, 0.f};
#pragma unroll
        for (int k0 = 0; k0 < DI_; k0 += 32) {
            bf16x8 a  = *(const bf16x8*)(&sxc[ar][k0 + lk]);
            bf16x8 bw = *(const bf16x8*)(Wx + (size_t)bcol * DI_ + k0 + lk);
            acc = __builtin_amdgcn_mfma_f32_16x16x32_bf16(a, bw, acc, 0, 0, 0);
        }
        int crow = (lane >> 4) * 4, ccol = lane & 15;
#pragma unroll
        for (int j = 0; j < 4; ++j) sxd[crow + j][wave * 16 + ccol] = acc[j];
    }
    __syncthreads();

    for (int idx = tid; idx < len * XD; idx += 384) {
        int l2 = idx / XD, col = idx % XD;
        xdout[((size_t)b*L_ + lbeg + l2)*XD + col] = sxd[l2][col];
    }

    float wreg[R_];
#pragma unroll
    for (int r = 0; r < R_; ++r) wreg[r] = Wd[d*R_ + r];
    float bdv = bd[d];
    float a[N_];
#pragma unroll
    for (int n = 0; n < N_; ++n) a[n] = -__expf(Al[d*N_ + n]);
    float h[N_], ap[N_];
#pragma unroll
    for (int n = 0; n < N_; ++n) { h[n] = 0.f; ap[n] = 1.f; }

    auto step = [&](int l2, float uv) {
        float dacc = bdv;
#pragma unroll
        for (int r = 0; r < R_; ++r) dacc = fmaf(wreg[r], sxd[l2][r], dacc);
        float dv = fmaxf(dacc, 0.f) + log1pf(__expf(-fabsf(dacc)));
        float du = dv * uv;
#pragma unroll
        for (int n = 0; n < N_; ++n) {
            float e = __expf(dv * a[n]);
            h[n] = fmaf(e, h[n], du * sxd[l2][R_ + n]);
            ap[n] *= e;
        }
    };
    if (len == LC_) {
#pragma unroll 4
        for (int l2 = 0; l2 < LC_; ++l2) step(l2, u[l2]);
    } else {
        for (int l2 = 0; l2 < len; ++l2) step(l2, u[l2]);
    }
    size_t base = (((size_t)(b*2 + br)*NC_ + c)*N_)*DI_ + d;
#pragma unroll
    for (int n = 0; n < N_; ++n) {
        hloc[base + (size_t)n*DI_]  = h[n];
        aprod[base + (size_t)n*DI_] = ap[n];
    }
}

// ---------------- serial combine over chunks (192 blocks x 256 thr) ----------------
__global__ void scan_combine(const float* __restrict__ hloc, const float* __restrict__ aprod,
                             float* __restrict__ hin) {
    int g = blockIdx.x * blockDim.x + threadIdx.x;
    int bb = g / (N_ * DI_);
    int rem = g % (N_ * DI_);
    float hrun = 0.f;
#pragma unroll
    for (int c = 0; c < NC_; ++c) {
        size_t idx = ((size_t)bb*NC_ + c)*N_*DI_ + rem;
        hin[idx] = hrun;
        hrun = fmaf(aprod[idx], hrun, hloc[idx]);
    }
}

// ---------------- scan phase 3: re-scan from hin, emit bf16 y ----------------
__global__ __launch_bounds__(192) void scan_part3(
                           const ushort_t* __restrict__ xc_f, const ushort_t* __restrict__ xc_b,
                           const float* __restrict__ xdbl_f, const float* __restrict__ xdbl_b,
                           const float* __restrict__ Wdt, const float* __restrict__ bdt,
                           const float* __restrict__ Wdtb, const float* __restrict__ bdtb,
                           const ushort_t* __restrict__ xz,
                           const float* __restrict__ Alog, const float* __restrict__ Alogb,
                           const float* __restrict__ Dpf, const float* __restrict__ Dpb,
                           const float* __restrict__ hin,
                           ushort_t* __restrict__ y_f, ushort_t* __restrict__ y_b) {
    int c = blockIdx.x, b = blockIdx.y >> 1, half = blockIdx.y & 1, br = blockIdx.z;
    int tid = threadIdx.x;
    int d = half * 192 + tid;
    const ushort_t* xc = br ? xc_b : xc_f;
    const float* xd = br ? xdbl_b : xdbl_f;
    const float* Wd = br ? Wdtb : Wdt;
    const float* bd = br ? bdtb : bdt;
    const float* Al = br ? Alogb : Alog;
    const float* Dpp = br ? Dpb : Dpf;
    ushort_t* y = br ? y_b : y_f;
    __shared__ float sdt[LC_][R_];
    __shared__ float sB[LC_][N_];
    __shared__ float sC[LC_][N_];
    int lbeg = c * LC_;
    int len = min(lbeg + LC_, L_) - lbeg;
    for (int idx = tid; idx < len*N_; idx += 192) {
        int l2 = idx >> 4, n = idx & 15;
        size_t row = (size_t)b*L_ + lbeg + l2;
        sB[l2][n] = xd[row*XD + R_ + n];
        sC[l2][n] = xd[row*XD + R_ + N_ + n];
    }
    for (int idx = tid; idx < len*R_; idx += 192) {
        int l2 = idx / R_, r = idx % R_;
        sdt[l2][r] = xd[((size_t)b*L_ + lbeg + l2)*XD + r];
    }
    __syncthreads();
    float wreg[R_];
#pragma unroll
    for (int r = 0; r < R_; ++r) wreg[r] = Wd[d*R_ + r];
    float bdv = bd[d];
    float a[N_];
#pragma unroll
    for (int n = 0; n < N_; ++n) a[n] = -__expf(Al[d*N_ + n]);
    float h[N_];
    size_t hbase = (((size_t)(b*2 + br)*NC_ + c)*N_)*DI_ + d;
#pragma unroll
    for (int n = 0; n < N_; ++n) h[n] = hin[hbase + (size_t)n*DI_];
    float dpv = Dpp[d];

    auto step = [&](int l2, float uv) {
        float dacc = bdv;
#pragma unroll
        for (int r = 0; r < R_; ++r) dacc = fmaf(wreg[r], sdt[l2][r], dacc);
        float dv = fmaxf(dacc, 0.f) + log1pf(__expf(-fabsf(dacc)));
        float du = dv * uv;
        float yv = 0.f;
#pragma unroll
        for (int n = 0; n < N_; ++n) {
            float e = __expf(dv * a[n]);
            h[n] = fmaf(e, h[n], du * sB[l2][n]);
            yv = fmaf(h[n], sC[l2][n], yv);
        }
        yv = fmaf(dpv, uv, yv);
        int lo = br ? (L_ - 1 - (lbeg + l2)) : (lbeg + l2);
        float zv = bf2f(xz[((size_t)b*L_ + lo)*E_ + DI_ + d]);
        y[((size_t)b*L_ + lo)*DI_ + d] = f2bf(yv * silu_f(zv));
    };
    if (len == LC_) {
        float u[LC_];
#pragma unroll
        for (int l2 = 0; l2 < LC_; ++l2)
            u[l2] = bf2f(xc[((size_t)b*L_ + lbeg + l2)*DI_ + d]);
#pragma unroll 4
        for (int l2 = 0; l2 < LC_; ++l2) step(l2, u[l2]);
    } else {
        for (int l2 = 0; l2 < len; ++l2)
            step(l2, bf2f(xc[((size_t)b*L_ + lbeg + l2)*DI_ + d]));
    }
}

// ---------------- fused out-proj + residual + rmsnorm + NEXT-layer in-proj ----------------
// grid 81 blocks x 384 thr (6 waves). Phase 1: out-proj (wave = 16 rows x 32 cols),
// residual add, rmsnorm -> hn in LDS. Phase 2 (!LAST): in-proj of layer l+1
// (wave = 16 rows x 128 cols, A from LDS) -> bf16 xzb.
template<bool LAST>
__global__ __launch_bounds__(384) void outproj_inproj(
    const ushort_t* __restrict__ yf, const ushort_t* __restrict__ yb,
    const ushort_t* __restrict__ Ww,        // Wout (layer l)
    const ushort_t* __restrict__ Win_next,  // Win (layer l+1); null if LAST
    float* __restrict__ residual, const float* __restrict__ nw,
    ushort_t* __restrict__ xzb_out, float* __restrict__ outp) {
    const int M = B_*L_;
    int wave = threadIdx.x >> 6, lane = threadIdx.x & 63;
    int m0 = blockIdx.x * 16;
    int lrow = lane & 15, lk = (lane >> 4) * 8;
    int crow = (lane >> 4) * 4, ccol = lane & 15;

    __shared__ ushort_t shn[16][D_ + 8];   // bf16 hn tile (stride 200 -> 2-way free)
    __shared__ float part[16][6];

    // ---- phase 1: out-proj, this wave covers cols [wave*32, wave*32+32) ----
    int n0 = wave * 32;
    f32x4 acc[2];
#pragma unroll
    for (int jn = 0; jn < 2; ++jn) acc[jn] = (f32x4){0.f, 0.f, 0.f, 0.f};
#pragma unroll 4
    for (int k0 = 0; k0 < DI_; k0 += 32) {
        int r = min(m0 + lrow, M - 1);
        bf16x8 vf = *(const bf16x8*)(yf + (size_t)r*DI_ + k0 + lk);
        bf16x8 vb = *(const bf16x8*)(yb + (size_t)r*DI_ + k0 + lk);
        bf16x8 a;
#pragma unroll
        for (int j = 0; j < 8; ++j)
            a[j] = (short)f2bf(0.5f*(bf2f((ushort_t)vf[j]) + bf2f((ushort_t)vb[j])));
        bf16x8 b[2];
#pragma unroll
        for (int jn = 0; jn < 2; ++jn) {
            int c = n0 + jn*16 + lrow;   // < 192 always
            b[jn] = *(const bf16x8*)(Ww + (size_t)c*DI_ + k0 + lk);
        }
#pragma unroll
        for (int jn = 0; jn < 2; ++jn)
            acc[jn] = __builtin_amdgcn_mfma_f32_16x16x32_bf16(a, b[jn], acc[jn], 0, 0, 0);
    }

    float resv[4][2];
    float sq[4] = {0.f, 0.f, 0.f, 0.f};
#pragma unroll
    for (int j = 0; j < 4; ++j) {
        int r = m0 + crow + j;
        bool ok = r < M;
#pragma unroll
        for (int jn = 0; jn < 2; ++jn) {
            int c = n0 + jn*16 + ccol;
            float v = ok ? (residual[(size_t)r*D_ + c] + acc[jn][j]) : 0.f;
            resv[j][jn] = v;
            sq[j] = fmaf(v, v, sq[j]);
        }
    }
#pragma unroll
    for (int m = 1; m < 16; m <<= 1)
#pragma unroll
        for (int j = 0; j < 4; ++j) sq[j] += __shfl_xor(sq[j], m, 64);
    if (ccol == 0) {
#pragma unroll
        for (int j = 0; j < 4; ++j) part[crow + j][wave] = sq[j];
    }
    __syncthreads();
#pragma unroll
    for (int j = 0; j < 4; ++j) {
        int r = m0 + crow + j;
        int rt = crow + j;
        float tot = part[rt][0] + part[rt][1] + part[rt][2]
                  + part[rt][3] + part[rt][4] + part[rt][5];
        float scale = rsqrtf(tot / (float)D_ + 1e-5f);
#pragma unroll
        for (int jn = 0; jn < 2; ++jn) {
            int c = n0 + jn*16 + ccol;
            float v = resv[j][jn];
            if (LAST) {
                if (r < M) outp[(size_t)r*D_ + c] = v * scale * nw[c];
            } else {
                if (r < M) residual[(size_t)r*D_ + c] = v;
                shn[rt][c] = f2bf(v * scale * nw[c]);   // garbage rows ok (stores guarded below)
            }
        }
    }
    if (LAST) return;
    __syncthreads();

    // ---- phase 2: in-proj of layer l+1, this wave covers cols [wave*128, +128) ----
    int e0 = wave * 128;
    f32x4 acc2[8];
#pragma unroll
    for (int jn = 0; jn < 8; ++jn) acc2[jn] = (f32x4){0.f, 0.f, 0.f, 0.f};
#pragma unroll
    for (int k0 = 0; k0 < D_; k0 += 32) {
        bf16x8 a = *(const bf16x8*)(&shn[lrow][k0 + lk]);
        bf16x8 b[8];
#pragma unroll
        for (int jn = 0; jn < 8; ++jn) {
            int c = e0 + jn*16 + lrow;   // < 768 always
            b[jn] = *(const bf16x8*)(Win_next + (size_t)c*D_ + k0 + lk);
        }
#pragma unroll
        for (int jn = 0; jn < 8; ++jn)
            acc2[jn] = __builtin_amdgcn_mfma_f32_16x16x32_bf16(a, b[jn], acc2[jn], 0, 0, 0);
    }
#pragma unroll
    for (int jn = 0; jn < 8; ++jn) {
        int c = e0 + jn*16 + ccol;
#pragma unroll
        for (int j = 0; j < 4; ++j) {
            int r = m0 + crow + j;
            if (r < M) xzb_out[(size_t)r*E_ + c] = f2bf(acc2[jn][j]);
        }
    }
}

extern "C" void kernel_launch(void* const* d_in, const int* in_sizes, int n_in,
                              void* d_out, int out_size, void* d_ws, size_t ws_size,
                              hipStream_t stream) {
    const float* xs     = (const float*)d_in[0];
    const float* xt     = (const float*)d_in[1];
    const float* pw     = (const float*)d_in[2];
    const float* pb     = (const float*)d_in[3];
    const float* cls    = (const float*)d_in[4];
    const float* pos    = (const float*)d_in[5];
    const float* Win    = (const float*)d_in[6];
    const float* convw  = (const float*)d_in[7];
    const float* convb  = (const float*)d_in[8];
    const float* Wx     = (const float*)d_in[9];
    const float* Wdt    = (const float*)d_in[10];
    const float* bdt    = (const float*)d_in[11];
    const float* Alog   = (const float*)d_in[12];
    const float* Dp     = (const float*)d_in[13];
    const float* convwb = (const float*)d_in[14];
    const float* convbb = (const float*)d_in[15];
    const float* Wxb    = (const float*)d_in[16];
    const float* Wdtb   = (const float*)d_in[17];
    const float* bdtb   = (const float*)d_in[18];
    const float* Alogb  = (const float*)d_in[19];
    const float* Dpb    = (const float*)d_in[20];
    const float* Wout   = (const float*)d_in[21];
    const float* normw  = (const float*)d_in[22];
    const float* normwf = (const float*)d_in[23];
    float* out = (float*)d_out;

    float* ws = (float*)d_ws;
    size_t off = 0;
    auto alloc = [&](size_t nfloats) { float* p = ws + off; off += nfloats; return p; };
    const size_t BL = (size_t)B_ * L_;
    const size_t CHNK = (size_t)B_ * 2 * NC_ * N_ * DI_;

    float*    residual = alloc(BL * D_);
    ushort_t* hn_bf    = (ushort_t*)alloc(BL * D_ / 2);
    ushort_t* xzb_bf   = (ushort_t*)alloc(BL * E_ / 2);
    ushort_t* xcf_bf   = (ushort_t*)alloc(BL * DI_ / 2);
    ushort_t* xcb_bf   = (ushort_t*)alloc(BL * DI_ / 2);
    float*    xdbl_f   = alloc(BL * XD);
    float*    xdbl_b   = alloc(BL * XD);
    ushort_t* y_f      = (ushort_t*)alloc(BL * DI_ / 2);
    ushort_t* y_b      = (ushort_t*)alloc(BL * DI_ / 2);
    float*    hloc     = alloc(CHNK);
    float*    aprod    = alloc(CHNK);
    float*    hin      = alloc(CHNK);
    ushort_t* pw_bf    = (ushort_t*)alloc((size_t)D_ * 768 / 2);
    ushort_t* Win_bf   = (ushort_t*)alloc((size_t)DEPTH_ * E_ * D_ / 2);
    ushort_t* Wx_bf    = (ushort_t*)alloc((size_t)DEPTH_ * XD * DI_ / 2);
    ushort_t* Wxb_bf   = (ushort_t*)alloc((size_t)DEPTH_ * XD * DI_ / 2);
    ushort_t* Wout_bf  = (ushort_t*)alloc((size_t)DEPTH_ * D_ * DI_ / 2);
    (void)ws_size; (void)in_sizes; (void)n_in; (void)out_size;

    // one-time weight conversions (single multi-segment kernel)
    cvt_bf16_multi<<<dim3(2048), dim3(256), 0, stream>>>(
        pw,   pw_bf,   D_ * 768,
        Win,  Win_bf,  DEPTH_ * E_ * D_,
        Wx,   Wx_bf,   DEPTH_ * XD * DI_,
        Wxb,  Wxb_bf,  DEPTH_ * XD * DI_,
        Wout, Wout_bf, DEPTH_ * D_ * DI_);

    // patch embed -> residual + hn (pmat scratch in hloc, tokmat in aprod)
    ushort_t* pmat   = (ushort_t*)hloc;
    float*    tokmat = aprod;
    im2col_kernel<<<dim3(B_ * 320), dim3(256), 0, stream>>>(xs, xt, pmat);
    mfma_gemm<2, 2, 2, 2, 0, 768><<<dim3(3, 20), dim3(256), 0, stream>>>(
        pmat, pw_bf, tokmat, nullptr, B_ * 320, D_);
    tok_rms<<<dim3(B_ * L_), dim3(192), 0, stream>>>(tokmat, pb, cls, pos, normw, residual, hn_bf);
    // layer-0 in-proj (hn from global); later layers get xzb from outproj_inproj
    mfma_gemm<2, 2, 2, 2, 1, 192><<<dim3(12, 21), dim3(256), 0, stream>>>(
        hn_bf, Win_bf, nullptr, xzb_bf, (int)BL, E_);

    for (int layer = 0; layer < DEPTH_; ++layer) {
        const ushort_t* Wx_l   = Wx_bf   + (size_t)layer * XD * DI_;
        const ushort_t* Wxb_l  = Wxb_bf  + (size_t)layer * XD * DI_;
        const ushort_t* Wout_l = Wout_bf + (size_t)layer * D_ * DI_;
        const float* cw_l    = convw  + (size_t)layer * DI_ * 4;
        const float* cb_l    = convb  + (size_t)layer * DI_;
        const float* cwb_l   = convwb + (size_t)layer * DI_ * 4;
        const float* cbb_l   = convbb + (size_t)layer * DI_;
        const float* Wdt_l   = Wdt    + (size_t)layer * DI_ * R_;
        const float* Wdtb_l  = Wdtb   + (size_t)layer * DI_ * R_;
        const float* bdt_l   = bdt    + (size_t)layer * DI_;
        const float* bdtb_l  = bdtb   + (size_t)layer * DI_;
        const float* Alog_l  = Alog   + (size_t)layer * DI_ * N_;
        const float* Alogb_l = Alogb  + (size_t)layer * DI_ * N_;
        const float* Dp_l    = Dp     + (size_t)layer * DI_;
        const float* Dpb_l   = Dpb    + (size_t)layer * DI_;

        scan1_conv<<<dim3(NC_, B_, 2), dim3(384), 0, stream>>>(
            xzb_bf, Wx_l, Wxb_l, cw_l, cb_l, cwb_l, cbb_l,
            Wdt_l, bdt_l, Wdtb_l, bdtb_l, Alog_l, Alogb_l,
            xcf_bf, xcb_bf, xdbl_f, xdbl_b, hloc, aprod);
        scan_combine<<<dim3((B_*2*N_*DI_)/256), dim3(256), 0, stream>>>(hloc, aprod, hin);
        scan_part3<<<dim3(NC_, B_ * 2, 2), dim3(192), 0, stream>>>(
            xcf_bf, xcb_bf, xdbl_f, xdbl_b, Wdt_l, bdt_l, Wdtb_l, bdtb_l, xzb_bf,
            Alog_l, Alogb_l, Dp_l, Dpb_l, hin, y_f, y_b);
        if (layer < DEPTH_ - 1) {
            outproj_inproj<false><<<dim3(81), dim3(384), 0, stream>>>(
                y_f, y_b, Wout_l, Win_bf + (size_t)(layer + 1) * E_ * D_,
                residual, normw + (size_t)(layer + 1) * D_, xzb_bf, nullptr);
        } else {
            outproj_inproj<true><<<dim3(81), dim3(384), 0, stream>>>(
                y_f, y_b, Wout_l, nullptr, residual, normwf, nullptr, out);
        }
    }
}

// Round 17
// 1728.458 us; speedup vs baseline: 1.0659x; 1.0659x over previous
//
#include <hip/hip_runtime.h>
#include <math.h>

#define B_ 4
#define L_ 321
#define D_ 192
#define DI_ 384
#define E_ 768      // 2*DI
#define R_ 12
#define N_ 16
#define DEPTH_ 24
#define XD 44       // R + 2N

#define NC_ 21      // number of scan chunks
#define LC_ 16      // chunk length (NC_*LC_ >= L_)

typedef __attribute__((ext_vector_type(8))) short bf16x8;
typedef __attribute__((ext_vector_type(4))) float f32x4;
typedef unsigned short ushort_t;

__device__ __forceinline__ float silu_f(float x) { return x / (1.f + __expf(-x)); }

__device__ __forceinline__ ushort_t f2bf(float x) {
    union { float f; unsigned u; } v; v.f = x;
    return (ushort_t)((v.u + 0x7fffu + ((v.u >> 16) & 1u)) >> 16);
}
__device__ __forceinline__ float bf2f(ushort_t h) {
    union { unsigned u; float f; } v; v.u = ((unsigned)h) << 16; return v.f;
}

// ---------------- one-shot multi-segment f32 -> bf16 (weights) ----------------
__global__ void cvt_bf16_multi(const float* __restrict__ s0, ushort_t* __restrict__ d0, int n0,
                               const float* __restrict__ s1, ushort_t* __restrict__ d1, int n1,
                               const float* __restrict__ s2, ushort_t* __restrict__ d2, int n2,
                               const float* __restrict__ s3, ushort_t* __restrict__ d3, int n3,
                               const float* __restrict__ s4, ushort_t* __restrict__ d4, int n4) {
    int total = n0 + n1 + n2 + n3 + n4;
    for (int i = blockIdx.x * blockDim.x + threadIdx.x; i < total; i += gridDim.x * blockDim.x) {
        int j = i;
        const float* s; ushort_t* d;
        if (j < n0) { s = s0; d = d0; }
        else { j -= n0;
            if (j < n1) { s = s1; d = d1; }
            else { j -= n1;
                if (j < n2) { s = s2; d = d2; }
                else { j -= n2;
                    if (j < n3) { s = s3; d = d3; }
                    else { j -= n3; s = s4; d = d4; }
                }
            }
        }
        d[j] = f2bf(s[j]);
    }
}

// ---------------- im2col for patch embed (writes bf16) ----------------
__global__ void im2col_kernel(const float* __restrict__ xs, const float* __restrict__ xt,
                              ushort_t* __restrict__ pm) {
    int p_all = blockIdx.x % 320;
    int b = blockIdx.x / 320;
    const float* src; int i, j, W;
    if (p_all < 64) { int p = p_all; i = p >> 3; j = p & 7; W = 128; src = xt + (size_t)b*3*128*128; }
    else            { int p = p_all - 64; i = p >> 4; j = p & 15; W = 256; src = xs + (size_t)b*3*256*256; }
    ushort_t* dst = pm + (size_t)blockIdx.x * 768;
    for (int m = threadIdx.x; m < 768; m += blockDim.x) {
        int c = m >> 8, rem = m & 255, pp = rem >> 4, qq = rem & 15;
        dst[m] = f2bf(src[(size_t)(c*W + i*16 + pp)*W + j*16 + qq]);
    }
}

// ---------------- scatter tokens + cls + pos -> residual, fused rmsnorm -> hn ----------------
__global__ void tok_rms(const float* __restrict__ tokmat, const float* __restrict__ pb,
                        const float* __restrict__ cls, const float* __restrict__ pos,
                        const float* __restrict__ normw,
                        float* __restrict__ residual, ushort_t* __restrict__ hn) {
    int blk = blockIdx.x;
    int b = blk / L_, t = blk % L_;
    int d = threadIdx.x;
    float v;
    if (t == 160) v = cls[d];
    else {
        int p = (t < 160) ? t : t - 1;
        v = tokmat[(size_t)(b*320 + p)*D_ + d] + pb[d];
    }
    v += pos[t*D_ + d];
    residual[(size_t)blk*D_ + d] = v;
    float sq = v * v;
#pragma unroll
    for (int m = 1; m < 64; m <<= 1) sq += __shfl_xor(sq, m, 64);
    __shared__ float part[3];
    int wave = d >> 6, lane = d & 63;
    if (lane == 0) part[wave] = sq;
    __syncthreads();
    float tot = part[0] + part[1] + part[2];
    float scale = rsqrtf(tot / (float)D_ + 1e-5f);
    hn[(size_t)blk*D_ + d] = f2bf(v * scale * normw[d]);
}

// ---------------- MFMA bf16 GEMM: C(MxN) = A(MxK,bf16) * B(NxK,bf16)^T ----------------
// KK compile-time. CMODE 0: C f32.  CMODE 1: C bf16.
template<int WM, int WN, int MFR, int NFR, int CMODE, int KK>
__global__ __launch_bounds__(WM*WN*64) void mfma_gemm(const ushort_t* __restrict__ A,
                          const ushort_t* __restrict__ Bw,
                          float* __restrict__ Cf, ushort_t* __restrict__ Ch,
                          int M, int N) {
    constexpr int BM = WM * MFR * 16;
    constexpr int BN = WN * NFR * 16;
    int bx = blockIdx.x, by = blockIdx.y;
    int wave = threadIdx.x >> 6, lane = threadIdx.x & 63;
    int wr = wave / WN, wc = wave % WN;
    int m0 = by * BM + wr * MFR * 16;
    int n0 = bx * BN + wc * NFR * 16;
    int lrow = lane & 15;
    int lk   = (lane >> 4) * 8;

    f32x4 acc[MFR][NFR];
#pragma unroll
    for (int i = 0; i < MFR; ++i)
#pragma unroll
        for (int j = 0; j < NFR; ++j) acc[i][j] = (f32x4){0.f, 0.f, 0.f, 0.f};

#pragma unroll 6
    for (int k0 = 0; k0 < KK; k0 += 32) {
        bf16x8 a[MFR], b[NFR];
#pragma unroll
        for (int i = 0; i < MFR; ++i) {
            int r = m0 + i*16 + lrow; r = min(r, M - 1);
            a[i] = *(const bf16x8*)(A + (size_t)r*KK + k0 + lk);
        }
#pragma unroll
        for (int jn = 0; jn < NFR; ++jn) {
            int c = n0 + jn*16 + lrow; c = min(c, N - 1);
            b[jn] = *(const bf16x8*)(Bw + (size_t)c*KK + k0 + lk);
        }
#pragma unroll
        for (int i = 0; i < MFR; ++i)
#pragma unroll
            for (int jn = 0; jn < NFR; ++jn)
                acc[i][jn] = __builtin_amdgcn_mfma_f32_16x16x32_bf16(a[i], b[jn], acc[i][jn], 0, 0, 0);
    }

    int crow = (lane >> 4) * 4;
    int ccol = lane & 15;
#pragma unroll
    for (int i = 0; i < MFR; ++i)
#pragma unroll
        for (int jn = 0; jn < NFR; ++jn) {
            int c = n0 + jn*16 + ccol;
            if (c >= N) continue;
#pragma unroll
            for (int j = 0; j < 4; ++j) {
                int r = m0 + i*16 + crow + j;
                if (r < M) {
                    if (CMODE == 0) Cf[(size_t)r*N + c] = acc[i][jn][j];
                    else            Ch[(size_t)r*N + c] = f2bf(acc[i][jn][j]);
                }
            }
        }
}

// ---------------- fused conv + xdbl GEMM + scan phase 1 ----------------
// grid (NC_, B_, 2), 384 threads (6 waves).
__global__ __launch_bounds__(384) void scan1_conv(
    const ushort_t* __restrict__ xzb,
    const ushort_t* __restrict__ Wxf, const ushort_t* __restrict__ Wxbw,
    const float* __restrict__ cw, const float* __restrict__ cb,
    const float* __restrict__ cwb, const float* __restrict__ cbb,
    const float* __restrict__ Wdt, const float* __restrict__ bdt,
    const float* __restrict__ Wdtb, const float* __restrict__ bdtb,
    const float* __restrict__ Alog, const float* __restrict__ Alogb,
    ushort_t* __restrict__ xc_f, ushort_t* __restrict__ xc_b,
    float* __restrict__ xdbl_f, float* __restrict__ xdbl_b,
    float* __restrict__ hloc, float* __restrict__ aprod) {
    int c = blockIdx.x, b = blockIdx.y, br = blockIdx.z;
    int tid = threadIdx.x, wave = tid >> 6, lane = tid & 63;
    const ushort_t* Wx = br ? Wxbw : Wxf;
    const float* cwp = br ? cwb : cw;
    const float* cbp = br ? cbb : cb;
    const float* Wd = br ? Wdtb : Wdt;
    const float* bd = br ? bdtb : bdt;
    const float* Al = br ? Alogb : Alog;
    ushort_t* xcout = br ? xc_b : xc_f;
    float* xdout = br ? xdbl_b : xdbl_f;

    __shared__ ushort_t sxc[LC_][DI_ + 8];
    __shared__ float sxd[LC_][48];
    int lbeg = c * LC_;
    int len = min(lbeg + LC_, L_) - lbeg;
    int d = tid;

    float4 w4 = *(const float4*)(cwp + (size_t)d*4);
    float b0 = cbp[d];
    const ushort_t* xrow = xzb + (size_t)b*L_*E_ + d;
    float u[LC_];
    if (len == LC_) {
        float xr[LC_ + 3];
#pragma unroll
        for (int t2 = 0; t2 < LC_ + 3; ++t2) {
            int t = lbeg - 3 + t2;
            float v = 0.f;
            if (t >= 0) { int tr = br ? (L_ - 1 - t) : t; v = bf2f(xrow[(size_t)tr*E_]); }
            xr[t2] = v;
        }
#pragma unroll
        for (int l2 = 0; l2 < LC_; ++l2) {
            float acc = b0;
            acc = fmaf(w4.x, xr[l2 + 0], acc);
            acc = fmaf(w4.y, xr[l2 + 1], acc);
            acc = fmaf(w4.z, xr[l2 + 2], acc);
            acc = fmaf(w4.w, xr[l2 + 3], acc);
            ushort_t hv = f2bf(silu_f(acc));
            sxc[l2][d] = hv;
            u[l2] = bf2f(hv);
            xcout[((size_t)b*L_ + lbeg + l2)*DI_ + d] = hv;
        }
    } else {
        for (int l2 = 0; l2 < len; ++l2) {
            int l = lbeg + l2;
            float acc = b0;
#pragma unroll
            for (int k = 0; k < 4; ++k) {
                int t = l - 3 + k;
                if (t >= 0) {
                    int tr = br ? (L_ - 1 - t) : t;
                    acc = fmaf(((const float*)&w4)[k], bf2f(xrow[(size_t)tr*E_]), acc);
                }
            }
            ushort_t hv = f2bf(silu_f(acc));
            sxc[l2][d] = hv;
            u[l2] = bf2f(hv);
            xcout[((size_t)b*L_ + lbeg + l2)*DI_ + d] = hv;
        }
    }
    __syncthreads();

    if (wave < 3) {
        int lrow = lane & 15, lk = (lane >> 4) * 8;
        int ar = min(lrow, len - 1);
        int bcol = min(wave * 16 + lrow, XD - 1);
        f32x4 acc = (f32x4){0.f, 0.f, 0.f, 0.f};
#pragma unroll
        for (int k0 = 0; k0 < DI_; k0 += 32) {
            bf16x8 a  = *(const bf16x8*)(&sxc[ar][k0 + lk]);
            bf16x8 bw = *(const bf16x8*)(Wx + (size_t)bcol * DI_ + k0 + lk);
            acc = __builtin_amdgcn_mfma_f32_16x16x32_bf16(a, bw, acc, 0, 0, 0);
        }
        int crow = (lane >> 4) * 4, ccol = lane & 15;
#pragma unroll
        for (int j = 0; j < 4; ++j) sxd[crow + j][wave * 16 + ccol] = acc[j];
    }
    __syncthreads();

    for (int idx = tid; idx < len * XD; idx += 384) {
        int l2 = idx / XD, col = idx % XD;
        xdout[((size_t)b*L_ + lbeg + l2)*XD + col] = sxd[l2][col];
    }

    float wreg[R_];
#pragma unroll
    for (int r = 0; r < R_; ++r) wreg[r] = Wd[d*R_ + r];
    float bdv = bd[d];
    float a[N_];
#pragma unroll
    for (int n = 0; n < N_; ++n) a[n] = -__expf(Al[d*N_ + n]);
    float h[N_], ap[N_];
#pragma unroll
    for (int n = 0; n < N_; ++n) { h[n] = 0.f; ap[n] = 1.f; }

    auto step = [&](int l2, float uv) {
        float dacc = bdv;
#pragma unroll
        for (int r = 0; r < R_; ++r) dacc = fmaf(wreg[r], sxd[l2][r], dacc);
        float dv = fmaxf(dacc, 0.f) + log1pf(__expf(-fabsf(dacc)));
        float du = dv * uv;
#pragma unroll
        for (int n = 0; n < N_; ++n) {
            float e = __expf(dv * a[n]);
            h[n] = fmaf(e, h[n], du * sxd[l2][R_ + n]);
            ap[n] *= e;
        }
    };
    if (len == LC_) {
#pragma unroll 4
        for (int l2 = 0; l2 < LC_; ++l2) step(l2, u[l2]);
    } else {
        for (int l2 = 0; l2 < len; ++l2) step(l2, u[l2]);
    }
    size_t base = (((size_t)(b*2 + br)*NC_ + c)*N_)*DI_ + d;
#pragma unroll
    for (int n = 0; n < N_; ++n) {
        hloc[base + (size_t)n*DI_]  = h[n];
        aprod[base + (size_t)n*DI_] = ap[n];
    }
}

// ---------------- serial combine over chunks (192 blocks x 256 thr) ----------------
__global__ void scan_combine(const float* __restrict__ hloc, const float* __restrict__ aprod,
                             float* __restrict__ hin) {
    int g = blockIdx.x * blockDim.x + threadIdx.x;
    int bb = g / (N_ * DI_);
    int rem = g % (N_ * DI_);
    float hrun = 0.f;
#pragma unroll
    for (int c = 0; c < NC_; ++c) {
        size_t idx = ((size_t)bb*NC_ + c)*N_*DI_ + rem;
        hin[idx] = hrun;
        hrun = fmaf(aprod[idx], hrun, hloc[idx]);
    }
}

// ---------------- scan phase 3: re-scan from hin, emit bf16 y ----------------
__global__ __launch_bounds__(192) void scan_part3(
                           const ushort_t* __restrict__ xc_f, const ushort_t* __restrict__ xc_b,
                           const float* __restrict__ xdbl_f, const float* __restrict__ xdbl_b,
                           const float* __restrict__ Wdt, const float* __restrict__ bdt,
                           const float* __restrict__ Wdtb, const float* __restrict__ bdtb,
                           const ushort_t* __restrict__ xz,
                           const float* __restrict__ Alog, const float* __restrict__ Alogb,
                           const float* __restrict__ Dpf, const float* __restrict__ Dpb,
                           const float* __restrict__ hin,
                           ushort_t* __restrict__ y_f, ushort_t* __restrict__ y_b) {
    int c = blockIdx.x, b = blockIdx.y >> 1, half = blockIdx.y & 1, br = blockIdx.z;
    int tid = threadIdx.x;
    int d = half * 192 + tid;
    const ushort_t* xc = br ? xc_b : xc_f;
    const float* xd = br ? xdbl_b : xdbl_f;
    const float* Wd = br ? Wdtb : Wdt;
    const float* bd = br ? bdtb : bdt;
    const float* Al = br ? Alogb : Alog;
    const float* Dpp = br ? Dpb : Dpf;
    ushort_t* y = br ? y_b : y_f;
    __shared__ float sdt[LC_][R_];
    __shared__ float sB[LC_][N_];
    __shared__ float sC[LC_][N_];
    int lbeg = c * LC_;
    int len = min(lbeg + LC_, L_) - lbeg;
    for (int idx = tid; idx < len*N_; idx += 192) {
        int l2 = idx >> 4, n = idx & 15;
        size_t row = (size_t)b*L_ + lbeg + l2;
        sB[l2][n] = xd[row*XD + R_ + n];
        sC[l2][n] = xd[row*XD + R_ + N_ + n];
    }
    for (int idx = tid; idx < len*R_; idx += 192) {
        int l2 = idx / R_, r = idx % R_;
        sdt[l2][r] = xd[((size_t)b*L_ + lbeg + l2)*XD + r];
    }
    __syncthreads();
    float wreg[R_];
#pragma unroll
    for (int r = 0; r < R_; ++r) wreg[r] = Wd[d*R_ + r];
    float bdv = bd[d];
    float a[N_];
#pragma unroll
    for (int n = 0; n < N_; ++n) a[n] = -__expf(Al[d*N_ + n]);
    float h[N_];
    size_t hbase = (((size_t)(b*2 + br)*NC_ + c)*N_)*DI_ + d;
#pragma unroll
    for (int n = 0; n < N_; ++n) h[n] = hin[hbase + (size_t)n*DI_];
    float dpv = Dpp[d];

    auto step = [&](int l2, float uv) {
        float dacc = bdv;
#pragma unroll
        for (int r = 0; r < R_; ++r) dacc = fmaf(wreg[r], sdt[l2][r], dacc);
        float dv = fmaxf(dacc, 0.f) + log1pf(__expf(-fabsf(dacc)));
        float du = dv * uv;
        float yv = 0.f;
#pragma unroll
        for (int n = 0; n < N_; ++n) {
            float e = __expf(dv * a[n]);
            h[n] = fmaf(e, h[n], du * sB[l2][n]);
            yv = fmaf(h[n], sC[l2][n], yv);
        }
        yv = fmaf(dpv, uv, yv);
        int lo = br ? (L_ - 1 - (lbeg + l2)) : (lbeg + l2);
        float zv = bf2f(xz[((size_t)b*L_ + lo)*E_ + DI_ + d]);
        y[((size_t)b*L_ + lo)*DI_ + d] = f2bf(yv * silu_f(zv));
    };
    if (len == LC_) {
        float u[LC_];
#pragma unroll
        for (int l2 = 0; l2 < LC_; ++l2)
            u[l2] = bf2f(xc[((size_t)b*L_ + lbeg + l2)*DI_ + d]);
#pragma unroll 4
        for (int l2 = 0; l2 < LC_; ++l2) step(l2, u[l2]);
    } else {
        for (int l2 = 0; l2 < len; ++l2)
            step(l2, bf2f(xc[((size_t)b*L_ + lbeg + l2)*DI_ + d]));
    }
}

// ---------------- fused out-proj + residual + rmsnorm -> hn/out (bf16 y in) ----------------
// grid 81 blocks x 256 thr. Averaged A-tile staged ONCE in LDS (was 4x redundant
// per-wave global loads + avg recompute).
template<bool LAST>
__global__ __launch_bounds__(256) void outproj_fused(
    const ushort_t* __restrict__ yf, const ushort_t* __restrict__ yb,
    const ushort_t* __restrict__ Ww,
    float* __restrict__ residual, const float* __restrict__ nw,
    ushort_t* __restrict__ hn, float* __restrict__ outp) {
    const int M = B_*L_, Nn = D_, K = DI_;
    int tid = threadIdx.x;
    int wave = tid >> 6, lane = tid & 63;
    int m0 = blockIdx.x * 16;
    int n0 = wave * 48;
    int lrow = lane & 15, lk = (lane >> 4) * 8;

    __shared__ ushort_t sy[16][DI_ + 8];   // avg-y tile; row stride 196 dw -> 2-way free
    // cooperative stage: 16 rows x 48 vectors of bf16x8
    for (int idx = tid; idx < 16 * (DI_ / 8); idx += 256) {
        int row = idx / (DI_ / 8), cv = idx % (DI_ / 8);
        int r = min(m0 + row, M - 1);
        bf16x8 vf = *(const bf16x8*)(yf + (size_t)r*K + cv*8);
        bf16x8 vb = *(const bf16x8*)(yb + (size_t)r*K + cv*8);
        bf16x8 a;
#pragma unroll
        for (int j = 0; j < 8; ++j)
            a[j] = (short)f2bf(0.5f*(bf2f((ushort_t)vf[j]) + bf2f((ushort_t)vb[j])));
        *(bf16x8*)(&sy[row][cv*8]) = a;
    }
    __syncthreads();

    f32x4 acc[3];
#pragma unroll
    for (int jn = 0; jn < 3; ++jn) acc[jn] = (f32x4){0.f, 0.f, 0.f, 0.f};

#pragma unroll 4
    for (int k0 = 0; k0 < K; k0 += 32) {
        bf16x8 a = *(const bf16x8*)(&sy[lrow][k0 + lk]);
        bf16x8 b[3];
#pragma unroll
        for (int jn = 0; jn < 3; ++jn) {
            int c = n0 + jn*16 + lrow;   // < 192 always
            b[jn] = *(const bf16x8*)(Ww + (size_t)c*K + k0 + lk);
        }
#pragma unroll
        for (int jn = 0; jn < 3; ++jn)
            acc[jn] = __builtin_amdgcn_mfma_f32_16x16x32_bf16(a, b[jn], acc[jn], 0, 0, 0);
    }

    int crow = (lane >> 4) * 4, ccol = lane & 15;
    float resv[4][3];
    float sq[4] = {0.f, 0.f, 0.f, 0.f};
#pragma unroll
    for (int j = 0; j < 4; ++j) {
        int r = m0 + crow + j;
        bool ok = r < M;
#pragma unroll
        for (int jn = 0; jn < 3; ++jn) {
            int c = n0 + jn*16 + ccol;
            float v = ok ? (residual[(size_t)r*Nn + c] + acc[jn][j]) : 0.f;
            resv[j][jn] = v;
            sq[j] = fmaf(v, v, sq[j]);
        }
    }
#pragma unroll
    for (int m = 1; m < 16; m <<= 1)
#pragma unroll
        for (int j = 0; j < 4; ++j) sq[j] += __shfl_xor(sq[j], m, 64);

    __shared__ float part[16][4];
    if (ccol == 0) {
#pragma unroll
        for (int j = 0; j < 4; ++j) part[crow + j][wave] = sq[j];
    }
    __syncthreads();
#pragma unroll
    for (int j = 0; j < 4; ++j) {
        int r = m0 + crow + j;
        if (r >= M) continue;
        int rt = crow + j;
        float tot = part[rt][0] + part[rt][1] + part[rt][2] + part[rt][3];
        float scale = rsqrtf(tot / (float)Nn + 1e-5f);
#pragma unroll
        for (int jn = 0; jn < 3; ++jn) {
            int c = n0 + jn*16 + ccol;
            float v = resv[j][jn];
            if (LAST) {
                outp[(size_t)r*Nn + c] = v * scale * nw[c];
            } else {
                residual[(size_t)r*Nn + c] = v;
                hn[(size_t)r*Nn + c] = f2bf(v * scale * nw[c]);
            }
        }
    }
}

extern "C" void kernel_launch(void* const* d_in, const int* in_sizes, int n_in,
                              void* d_out, int out_size, void* d_ws, size_t ws_size,
                              hipStream_t stream) {
    const float* xs     = (const float*)d_in[0];
    const float* xt     = (const float*)d_in[1];
    const float* pw     = (const float*)d_in[2];
    const float* pb     = (const float*)d_in[3];
    const float* cls    = (const float*)d_in[4];
    const float* pos    = (const float*)d_in[5];
    const float* Win    = (const float*)d_in[6];
    const float* convw  = (const float*)d_in[7];
    const float* convb  = (const float*)d_in[8];
    const float* Wx     = (const float*)d_in[9];
    const float* Wdt    = (const float*)d_in[10];
    const float* bdt    = (const float*)d_in[11];
    const float* Alog   = (const float*)d_in[12];
    const float* Dp     = (const float*)d_in[13];
    const float* convwb = (const float*)d_in[14];
    const float* convbb = (const float*)d_in[15];
    const float* Wxb    = (const float*)d_in[16];
    const float* Wdtb   = (const float*)d_in[17];
    const float* bdtb   = (const float*)d_in[18];
    const float* Alogb  = (const float*)d_in[19];
    const float* Dpb    = (const float*)d_in[20];
    const float* Wout   = (const float*)d_in[21];
    const float* normw  = (const float*)d_in[22];
    const float* normwf = (const float*)d_in[23];
    float* out = (float*)d_out;

    float* ws = (float*)d_ws;
    size_t off = 0;
    auto alloc = [&](size_t nfloats) { float* p = ws + off; off += nfloats; return p; };
    const size_t BL = (size_t)B_ * L_;
    const size_t CHNK = (size_t)B_ * 2 * NC_ * N_ * DI_;

    float*    residual = alloc(BL * D_);
    ushort_t* hn_bf    = (ushort_t*)alloc(BL * D_ / 2);
    ushort_t* xzb_bf   = (ushort_t*)alloc(BL * E_ / 2);
    ushort_t* xcf_bf   = (ushort_t*)alloc(BL * DI_ / 2);
    ushort_t* xcb_bf   = (ushort_t*)alloc(BL * DI_ / 2);
    float*    xdbl_f   = alloc(BL * XD);
    float*    xdbl_b   = alloc(BL * XD);
    ushort_t* y_f      = (ushort_t*)alloc(BL * DI_ / 2);
    ushort_t* y_b      = (ushort_t*)alloc(BL * DI_ / 2);
    float*    hloc     = alloc(CHNK);
    float*    aprod    = alloc(CHNK);
    float*    hin      = alloc(CHNK);
    ushort_t* pw_bf    = (ushort_t*)alloc((size_t)D_ * 768 / 2);
    ushort_t* Win_bf   = (ushort_t*)alloc((size_t)DEPTH_ * E_ * D_ / 2);
    ushort_t* Wx_bf    = (ushort_t*)alloc((size_t)DEPTH_ * XD * DI_ / 2);
    ushort_t* Wxb_bf   = (ushort_t*)alloc((size_t)DEPTH_ * XD * DI_ / 2);
    ushort_t* Wout_bf  = (ushort_t*)alloc((size_t)DEPTH_ * D_ * DI_ / 2);
    (void)ws_size; (void)in_sizes; (void)n_in; (void)out_size;

    // one-time weight conversions (single multi-segment kernel)
    cvt_bf16_multi<<<dim3(2048), dim3(256), 0, stream>>>(
        pw,   pw_bf,   D_ * 768,
        Win,  Win_bf,  DEPTH_ * E_ * D_,
        Wx,   Wx_bf,   DEPTH_ * XD * DI_,
        Wxb,  Wxb_bf,  DEPTH_ * XD * DI_,
        Wout, Wout_bf, DEPTH_ * D_ * DI_);

    // patch embed -> residual + hn (pmat scratch in hloc, tokmat in aprod)
    ushort_t* pmat   = (ushort_t*)hloc;
    float*    tokmat = aprod;
    im2col_kernel<<<dim3(B_ * 320), dim3(256), 0, stream>>>(xs, xt, pmat);
    mfma_gemm<2, 2, 2, 2, 0, 768><<<dim3(3, 20), dim3(256), 0, stream>>>(
        pmat, pw_bf, tokmat, nullptr, B_ * 320, D_);
    tok_rms<<<dim3(B_ * L_), dim3(192), 0, stream>>>(tokmat, pb, cls, pos, normw, residual, hn_bf);

    for (int layer = 0; layer < DEPTH_; ++layer) {
        const ushort_t* Win_l  = Win_bf  + (size_t)layer * E_ * D_;
        const ushort_t* Wx_l   = Wx_bf   + (size_t)layer * XD * DI_;
        const ushort_t* Wxb_l  = Wxb_bf  + (size_t)layer * XD * DI_;
        const ushort_t* Wout_l = Wout_bf + (size_t)layer * D_ * DI_;
        const float* cw_l    = convw  + (size_t)layer * DI_ * 4;
        const float* cb_l    = convb  + (size_t)layer * DI_;
        const float* cwb_l   = convwb + (size_t)layer * DI_ * 4;
        const float* cbb_l   = convbb + (size_t)layer * DI_;
        const float* Wdt_l   = Wdt    + (size_t)layer * DI_ * R_;
        const float* Wdtb_l  = Wdtb   + (size_t)layer * DI_ * R_;
        const float* bdt_l   = bdt    + (size_t)layer * DI_;
        const float* bdtb_l  = bdtb   + (size_t)layer * DI_;
        const float* Alog_l  = Alog   + (size_t)layer * DI_ * N_;
        const float* Alogb_l = Alogb  + (size_t)layer * DI_ * N_;
        const float* Dp_l    = Dp     + (size_t)layer * DI_;
        const float* Dpb_l   = Dpb    + (size_t)layer * DI_;

        // in-proj: M=1284, N=768, K=192 (compile-time) -> bf16 xzb directly
        mfma_gemm<2, 2, 2, 2, 1, 192><<<dim3(12, 21), dim3(256), 0, stream>>>(
            hn_bf, Win_l, nullptr, xzb_bf, (int)BL, E_);
        scan1_conv<<<dim3(NC_, B_, 2), dim3(384), 0, stream>>>(
            xzb_bf, Wx_l, Wxb_l, cw_l, cb_l, cwb_l, cbb_l,
            Wdt_l, bdt_l, Wdtb_l, bdtb_l, Alog_l, Alogb_l,
            xcf_bf, xcb_bf, xdbl_f, xdbl_b, hloc, aprod);
        scan_combine<<<dim3((B_*2*N_*DI_)/256), dim3(256), 0, stream>>>(hloc, aprod, hin);
        scan_part3<<<dim3(NC_, B_ * 2, 2), dim3(192), 0, stream>>>(
            xcf_bf, xcb_bf, xdbl_f, xdbl_b, Wdt_l, bdt_l, Wdtb_l, bdtb_l, xzb_bf,
            Alog_l, Alogb_l, Dp_l, Dpb_l, hin, y_f, y_b);
        if (layer < DEPTH_ - 1) {
            outproj_fused<false><<<dim3(81), dim3(256), 0, stream>>>(
                y_f, y_b, Wout_l, residual, normw + (size_t)(layer + 1) * D_, hn_bf, nullptr);
        } else {
            outproj_fused<true><<<dim3(81), dim3(256), 0, stream>>>(
                y_f, y_b, Wout_l, residual, normwf, nullptr, out);
        }
    }
}